// Round 9
// baseline (532.772 us; speedup 1.0000x reference)
//
#include <hip/hip_runtime.h>

#define NN 100000
#define NE 1600000
#define NF 256
#define HD 64
#define NC 32

#define BKS 8
#define NBK ((NN + 255) >> 8)      // 391 buckets of 256 nodes
#define CHUNK 4096                 // edges per bin_edges block
#define NBLK ((NE + CHUNK - 1) / CHUNK)  // 391

__device__ __forceinline__ float lrelu02(float x) { return fmaxf(x, 0.2f * x); }

// ---------------- CSR build via bucketed counting sort (unchanged from R7) ----------------

__global__ __launch_bounds__(256) void bucket_hist(const int* __restrict__ dst, int* __restrict__ gcnt) {
    __shared__ int hist[NBK];
    int tid = threadIdx.x;
    for (int i = tid; i < NBK; i += 256) hist[i] = 0;
    __syncthreads();
    int base = blockIdx.x * CHUNK;
    #pragma unroll
    for (int k = 0; k < CHUNK / 256; k++) {
        int i = base + k * 256 + tid;
        if (i < NE) atomicAdd(&hist[dst[i] >> BKS], 1);
    }
    __syncthreads();
    for (int i = tid; i < NBK; i += 256) if (hist[i]) atomicAdd(&gcnt[i], hist[i]);
}

__global__ void bucket_scan(const int* __restrict__ gcnt, int* __restrict__ gbase, int* __restrict__ gcur) {
    __shared__ int sh[512];
    int tid = threadIdx.x;
    int v = (tid < NBK) ? gcnt[tid] : 0;
    sh[tid] = v;
    __syncthreads();
    for (int d = 1; d < 512; d <<= 1) {
        int t = (tid >= d) ? sh[tid - d] : 0;
        __syncthreads();
        sh[tid] += t;
        __syncthreads();
    }
    if (tid < NBK) { int ex = sh[tid] - v; gbase[tid] = ex; gcur[tid] = ex; }
}

__global__ __launch_bounds__(256) void bin_edges(const int* __restrict__ src, const int* __restrict__ dst,
                                                 int* __restrict__ gcur, int2* __restrict__ ebuf) {
    __shared__ int hist[NBK];
    __shared__ int excl[NBK];
    __shared__ int runbase[NBK];
    __shared__ int ssum[256];
    __shared__ int2 sorted[CHUNK];   // 32 KB
    int tid = threadIdx.x;
    int base = blockIdx.x * CHUNK;
    int n = NE - base; if (n > CHUNK) n = CHUNK;

    for (int i = tid; i < NBK; i += 256) hist[i] = 0;
    __syncthreads();

    int2 ed[CHUNK / 256];
    int bk[CHUNK / 256];
    #pragma unroll
    for (int k = 0; k < CHUNK / 256; k++) {
        int i = base + k * 256 + tid;
        if (i < NE) {
            ed[k] = make_int2(src[i], dst[i]);
            bk[k] = ed[k].y >> BKS;
            atomicAdd(&hist[bk[k]], 1);
        } else bk[k] = -1;
    }
    __syncthreads();
    int h0 = (2 * tid < NBK) ? hist[2 * tid] : 0;
    int h1 = (2 * tid + 1 < NBK) ? hist[2 * tid + 1] : 0;
    ssum[tid] = h0 + h1;
    __syncthreads();
    for (int d = 1; d < 256; d <<= 1) {
        int t = (tid >= d) ? ssum[tid - d] : 0;
        __syncthreads();
        ssum[tid] += t;
        __syncthreads();
    }
    int pref = ssum[tid] - (h0 + h1);
    if (2 * tid < NBK) excl[2 * tid] = pref;
    if (2 * tid + 1 < NBK) excl[2 * tid + 1] = pref + h0;
    for (int b = tid; b < NBK; b += 256) {
        int c = hist[b];
        runbase[b] = c ? atomicAdd(&gcur[b], c) : 0;
    }
    __syncthreads();
    #pragma unroll
    for (int k = 0; k < CHUNK / 256; k++) {
        if (bk[k] >= 0) {
            int r = atomicAdd(&excl[bk[k]], 1);
            sorted[r] = ed[k];
        }
    }
    __syncthreads();
    for (int i = tid; i < n; i += 256) {
        int2 e = sorted[i];
        int b = e.y >> BKS;
        int local_rank = i - (excl[b] - hist[b]);
        ebuf[runbase[b] + local_rank] = e;
    }
}

__global__ __launch_bounds__(256) void bucket_csr(const int2* __restrict__ ebuf, const int* __restrict__ gbase,
                                                  const int* __restrict__ gcnt,
                                                  int* __restrict__ offs, int* __restrict__ csr) {
    __shared__ int hist[256], cur[256], ssum[256];
    int b = blockIdx.x, tid = threadIdx.x;
    int ebeg = gbase[b], cnt = gcnt[b];
    int node0 = b << BKS;
    hist[tid] = 0;
    __syncthreads();
    for (int i = ebeg + tid; i < ebeg + cnt; i += 256)
        atomicAdd(&hist[ebuf[i].y & 255], 1);
    __syncthreads();
    int v = hist[tid];
    ssum[tid] = v;
    __syncthreads();
    for (int d = 1; d < 256; d <<= 1) {
        int t = (tid >= d) ? ssum[tid - d] : 0;
        __syncthreads();
        ssum[tid] += t;
        __syncthreads();
    }
    int ex = ebeg + ssum[tid] - v;
    cur[tid] = ex;
    int nnode = NN - node0; if (nnode > 256) nnode = 256;
    if (tid < nnode) offs[node0 + tid] = ex;
    if (b == NBK - 1 && tid == nnode - 1) offs[NN] = ebeg + cnt;
    __syncthreads();
    for (int i = ebeg + tid; i < ebeg + cnt; i += 256) {
        int2 e = ebuf[i];
        int pos = atomicAdd(&cur[e.y & 255], 1);
        csr[pos] = e.x;
    }
}

// ---------------- 64-thread register-blocked GEMM: 8 nodes x 8 cols per thread ----------------
// Per k: 2 b128 x-reads (8-way lane-broadcast, free) + 2 b128 W-reads feed 64 FMAs.
// BN=64 (COUT=64) -> 1564 one-wave blocks (~6/CU residency, LDS 16.9 KB).

template <int CIN, int COUT>
__global__ __launch_bounds__(64) void rb_gemm(const float* __restrict__ in, const float* __restrict__ W,
                                              const float* __restrict__ a_s, const float* __restrict__ a_d,
                                              float* __restrict__ h, float* __restrict__ asv,
                                              float* __restrict__ adv) {
    const int KC  = 32;
    const int CGN = COUT / 8;        // col groups (8 or 4)
    const int NGN = 64 / CGN;        // node groups (8 or 16)
    const int BN  = NGN * 8;         // 64 or 128
    const int BNP = BN + 4;
    __shared__ float xsT[KC * BNP];
    __shared__ float Wl[KC * COUT];
    int tid = threadIdx.x;
    int cg = tid % CGN;
    int ng = tid / CGN;
    int c0 = cg * 8;
    int n0base = blockIdx.x * BN;

    float4 a0[8], a1[8];
    #pragma unroll
    for (int i = 0; i < 8; i++) { a0[i] = make_float4(0,0,0,0); a1[i] = make_float4(0,0,0,0); }

    for (int k0 = 0; k0 < CIN; k0 += KC) {
        __syncthreads();
        // stage x transposed (coalesced float4 global reads, scatter into xsT)
        #pragma unroll
        for (int f = tid; f < BN * KC / 4; f += 64) {
            int n = f >> 3;              // / (KC/4)
            int q = f & 7;
            int gn = n0base + n;
            float4 v = make_float4(0,0,0,0);
            if (gn < NN) v = *(const float4*)&in[(size_t)gn * CIN + k0 + q * 4];
            xsT[(q * 4 + 0) * BNP + n] = v.x;
            xsT[(q * 4 + 1) * BNP + n] = v.y;
            xsT[(q * 4 + 2) * BNP + n] = v.z;
            xsT[(q * 4 + 3) * BNP + n] = v.w;
        }
        // stage W chunk (row-major, coalesced)
        #pragma unroll
        for (int f = tid; f < KC * COUT / 4; f += 64)
            *(float4*)&Wl[f * 4] = *(const float4*)&W[(size_t)k0 * COUT + f * 4];
        __syncthreads();
        #pragma unroll 8
        for (int k = 0; k < KC; k++) {
            float4 xv0 = *(float4*)&xsT[k * BNP + ng * 8];
            float4 xv1 = *(float4*)&xsT[k * BNP + ng * 8 + 4];
            float4 w0 = *(float4*)&Wl[k * COUT + c0];
            float4 w1 = *(float4*)&Wl[k * COUT + c0 + 4];
            #pragma unroll
            for (int i = 0; i < 8; i++) {
                float xc;
                if (i < 4) xc = (i == 0) ? xv0.x : (i == 1) ? xv0.y : (i == 2) ? xv0.z : xv0.w;
                else       xc = (i == 4) ? xv1.x : (i == 5) ? xv1.y : (i == 6) ? xv1.z : xv1.w;
                a0[i].x += xc * w0.x; a0[i].y += xc * w0.y; a0[i].z += xc * w0.z; a0[i].w += xc * w0.w;
                a1[i].x += xc * w1.x; a1[i].y += xc * w1.y; a1[i].z += xc * w1.z; a1[i].w += xc * w1.w;
            }
        }
    }
    // epilogue
    float4 As0 = *(const float4*)&a_s[c0];
    float4 As1 = *(const float4*)&a_s[c0 + 4];
    float4 Ad0 = *(const float4*)&a_d[c0];
    float4 Ad1 = *(const float4*)&a_d[c0 + 4];
    #pragma unroll
    for (int i = 0; i < 8; i++) {
        int n = n0base + ng * 8 + i;
        if (n < NN) {
            *(float4*)&h[(size_t)n * COUT + c0] = a0[i];
            *(float4*)&h[(size_t)n * COUT + c0 + 4] = a1[i];
        }
        float vs = a0[i].x * As0.x + a0[i].y * As0.y + a0[i].z * As0.z + a0[i].w * As0.w
                 + a1[i].x * As1.x + a1[i].y * As1.y + a1[i].z * As1.z + a1[i].w * As1.w;
        float vd = a0[i].x * Ad0.x + a0[i].y * Ad0.y + a0[i].z * Ad0.z + a0[i].w * Ad0.w
                 + a1[i].x * Ad1.x + a1[i].y * Ad1.y + a1[i].z * Ad1.z + a1[i].w * Ad1.w;
        #pragma unroll
        for (int off = 1; off < CGN; off <<= 1) { vs += __shfl_xor(vs, off); vd += __shfl_xor(vd, off); }
        if (cg == 0 && n < NN) { asv[n] = vs; adv[n] = vd; }
    }
}

// ---------------- fused aggregate (unchanged from R7) ----------------

template <int C, bool ACT>
__global__ __launch_bounds__(256) void gat_agg(const float* __restrict__ h, const float* __restrict__ asv,
                                               const float* __restrict__ adv, const int* __restrict__ offs,
                                               const int* __restrict__ csr,
                                               const float* __restrict__ bias, float* __restrict__ out) {
    const int LPR = C / 4;
    const int G = 64 / LPR;
    const float4* h4 = (const float4*)h;
    int lane = threadIdx.x & 63;
    int v = blockIdx.x * 4 + (threadIdx.x >> 6);
    int beg = offs[v], end = offs[v + 1];
    int g = lane / LPR, r = lane % LPR;
    float adv_v = adv[v];

    float4 acc = {0.f, 0.f, 0.f, 0.f};
    float dsum = 0.f;
    #pragma unroll 4
    for (int e = beg + g; e < end; e += G) {
        int s = csr[e];
        float ww = __expf(lrelu02(asv[s] + adv_v));
        float4 hv = h4[(size_t)s * LPR + r];
        dsum += ww;
        acc.x += ww * hv.x; acc.y += ww * hv.y; acc.z += ww * hv.z; acc.w += ww * hv.w;
    }
    #pragma unroll
    for (int off = LPR; off < 64; off <<= 1) {
        acc.x += __shfl_xor(acc.x, off);
        acc.y += __shfl_xor(acc.y, off);
        acc.z += __shfl_xor(acc.z, off);
        acc.w += __shfl_xor(acc.w, off);
        dsum += __shfl_xor(dsum, off);
    }
    if (g == 0) {
        float selfw = __expf(lrelu02(asv[v] + adv_v));
        float4 hs = h4[(size_t)v * LPR + r];
        acc.x += selfw * hs.x; acc.y += selfw * hs.y;
        acc.z += selfw * hs.z; acc.w += selfw * hs.w;
        dsum += selfw;
        float inv = 1.f / (dsum + 1e-16f);
        float4 bb = ((const float4*)bias)[r];
        float4 o;
        o.x = acc.x * inv + bb.x; o.y = acc.y * inv + bb.y;
        o.z = acc.z * inv + bb.z; o.w = acc.w * inv + bb.w;
        if (ACT) {
            o.x = fmaxf(o.x, 0.01f * o.x); o.y = fmaxf(o.y, 0.01f * o.y);
            o.z = fmaxf(o.z, 0.01f * o.z); o.w = fmaxf(o.w, 0.01f * o.w);
        }
        ((float4*)out)[(size_t)v * LPR + r] = o;
    }
}

// ---------------- launch ----------------

extern "C" void kernel_launch(void* const* d_in, const int* in_sizes, int n_in,
                              void* d_out, int out_size, void* d_ws, size_t ws_size,
                              hipStream_t stream) {
    const float* x   = (const float*)d_in[0];
    const int*   ei  = (const int*)d_in[1];
    const float* W1  = (const float*)d_in[2];
    const float* as1 = (const float*)d_in[3];
    const float* ad1 = (const float*)d_in[4];
    const float* b1  = (const float*)d_in[5];
    const float* W2  = (const float*)d_in[6];
    const float* as2 = (const float*)d_in[7];
    const float* ad2 = (const float*)d_in[8];
    const float* b2  = (const float*)d_in[9];
    const float* W3  = (const float*)d_in[10];
    const float* as3 = (const float*)d_in[11];
    const float* ad3 = (const float*)d_in[12];
    const float* b3  = (const float*)d_in[13];
    float* out = (float*)d_out;

    const int* srcp = ei;
    const int* dstp = ei + NE;

    char* w = (char*)d_ws;
    float* h     = (float*)w;   w += sizeof(float) * (size_t)NN * HD;
    float* featB = (float*)w;   w += sizeof(float) * (size_t)NN * HD;
    float* asv   = (float*)w;   w += sizeof(float) * NN;
    float* advv  = (float*)w;   w += sizeof(float) * NN;
    int* offs    = (int*)w;     w += sizeof(int) * (NN + 1);
    int* csr     = (int*)w;     w += sizeof(int) * (size_t)NE;
    int2* ebuf   = (int2*)w;    w += sizeof(int2) * (size_t)NE;
    int* gcnt    = (int*)w;     w += sizeof(int) * NBK;
    int* gbase   = (int*)w;     w += sizeof(int) * NBK;
    int* gcur    = (int*)w;     w += sizeof(int) * NBK;

    const int GB64  = (NN + 63) / 64;     // BN=64 (COUT=64)
    const int GB128 = (NN + 127) / 128;   // BN=128 (COUT=32)

    // CSR build (bucketed counting sort; shared across all 3 layers)
    hipMemsetAsync(gcnt, 0, sizeof(int) * NBK, stream);
    bucket_hist<<<NBLK, 256, 0, stream>>>(dstp, gcnt);
    bucket_scan<<<1, 512, 0, stream>>>(gcnt, gbase, gcur);
    bin_edges<<<NBLK, 256, 0, stream>>>(srcp, dstp, gcur, ebuf);
    bucket_csr<<<NBK, 256, 0, stream>>>(ebuf, gbase, gcnt, offs, csr);

    // layer 1
    rb_gemm<NF, HD><<<GB64, 64, 0, stream>>>(x, W1, as1, ad1, h, asv, advv);
    gat_agg<HD, true><<<NN / 4, 256, 0, stream>>>(h, asv, advv, offs, csr, b1, featB);

    // layer 2
    rb_gemm<HD, HD><<<GB64, 64, 0, stream>>>(featB, W2, as2, ad2, h, asv, advv);
    gat_agg<HD, true><<<NN / 4, 256, 0, stream>>>(h, asv, advv, offs, csr, b2, featB);

    // layer 3
    rb_gemm<HD, NC><<<GB128, 64, 0, stream>>>(featB, W3, as3, ad3, h, asv, advv);
    gat_agg<NC, false><<<NN / 4, 256, 0, stream>>>(h, asv, advv, offs, csr, b3, out);
}